// Round 2
// baseline (2423.554 us; speedup 1.0000x reference)
//
#include <hip/hip_runtime.h>

// LevelwiseSTA v2: level-grouped compact records + single-pass CAS-LSE chain.
//
// Build: multisplit edges into 32 level buckets (block-chunk reservation in
// LDS -> coalesced window writes; fixes the 4.7x write-allocate inflation of
// the round-1 scatter). Record = 16B {src, dstLocal, 4 x bf16 d}; invalid
// slots encoded as bf16(-3e30) sentinel.
//
// Chain: per node x channel keep packed (float m, float s) in one 64-bit
// word; per level one kernel does an online logsumexp merge via atomicCAS.
// m is a max (order-invariant, exact classification); s has CAS-order fp
// noise ~1e-7 rel, far under tolerance. Unreachable propagates as exactly
// -1e30 (fp32 absorption), matching the reference bitwise.

#define NEG_INF  (-1e30f)
#define TAU_F    (0.07f)
#define INV_TAU  (1.0f / 0.07f)

typedef unsigned int uint;
typedef unsigned long long u64;

__device__ __forceinline__ uint bf16_of(float f) {
    uint u = __float_as_uint(f);
    u += 0x7FFFu + ((u >> 16) & 1u);    // round to nearest even
    return u >> 16;
}
__device__ __forceinline__ float f_of_bf16(uint h) {
    return __uint_as_float((h & 0xFFFFu) << 16);
}

// ----------------------------------------------------------------- hist / scan
__global__ void k_hist32(const int* __restrict__ dst, int E, int per,
                         int* __restrict__ lvlCnt) {
    __shared__ int h[32];
    int t = threadIdx.x;
    if (t < 32) h[t] = 0;
    __syncthreads();
    int i = blockIdx.x * blockDim.x + t;
    int st = gridDim.x * blockDim.x;
    for (; i < E; i += st) {
        int l = dst[i] / per; if (l > 31) l = 31;
        atomicAdd(&h[l], 1);
    }
    __syncthreads();
    if (t < 32) atomicAdd(&lvlCnt[t], h[t]);
}

__global__ void k_scan32(const int* __restrict__ lvlCnt,
                         int* __restrict__ lvlBase, int* __restrict__ lvlCur) {
    if (threadIdx.x == 0) {
        int acc = 0;
        for (int l = 0; l < 32; ++l) {
            lvlBase[l] = acc; lvlCur[l] = acc; acc += lvlCnt[l];
        }
        lvlBase[32] = acc;
    }
}

// -------------------------------------------------------------------- init
// state[node] = {bits(m_r), bits(s_r), bits(m_f), bits(s_f)}; (m,s) pairs are
// 8B-aligned CAS targets. Level-0 nodes: m=input, s=1 (at = m + tau*log 1).
// Others: m=input(=-1e30), s=0.
__global__ void k_init(const float2* __restrict__ ia, int N, int per,
                       uint4* __restrict__ state) {
    int i = blockIdx.x * blockDim.x + threadIdx.x;
    int st = gridDim.x * blockDim.x;
    for (; i < N; i += st) {
        float2 a = ia[i];
        float s = (i < per) ? 1.0f : 0.0f;
        uint4 v;
        v.x = __float_as_uint(a.x); v.y = __float_as_uint(s);
        v.z = __float_as_uint(a.y); v.w = __float_as_uint(s);
        state[i] = v;
    }
}

// ------------------------------------------------------------------- stage1
// Multisplit into 32 level buckets with per-chunk reservation.
#define CHUNK 4096
__global__ __launch_bounds__(256) void k_stage1(
        const int* __restrict__ srcA, const int* __restrict__ dstA,
        const float4* __restrict__ dh, const float4* __restrict__ mk,
        int E, int per, int* __restrict__ lvlCur, uint4* __restrict__ recs) {
    __shared__ int h[32], bs[32], h2[32];
    int nChunk = (E + CHUNK - 1) / CHUNK;
    for (int c = blockIdx.x; c < nChunk; c += gridDim.x) {
        int t = threadIdx.x;
        if (t < 32) { h[t] = 0; h2[t] = 0; }
        __syncthreads();
        int base = c * CHUNK;
        unsigned char lv[16];
        int ds[16];
#pragma unroll
        for (int k = 0; k < 16; ++k) {
            int i = base + k * 256 + t;
            int l = 255, d = 0;
            if (i < E) {
                d = dstA[i];
                l = d / per; if (l > 31) l = 31;
                atomicAdd(&h[l], 1);
            }
            lv[k] = (unsigned char)l; ds[k] = d;
        }
        __syncthreads();
        if (t < 32 && h[t] > 0) bs[t] = atomicAdd(&lvlCur[t], h[t]);
        __syncthreads();
        const uint INVB = bf16_of(-3e30f);
#pragma unroll
        for (int k = 0; k < 16; ++k) {
            int i = base + k * 256 + t;
            if (i >= E) continue;
            int l = lv[k];
            float4 dv = dh[i];
            float4 mv = mk[i];
            uint e0 = (mv.x > 0.5f) ? bf16_of(dv.x * mv.x) : INVB;
            uint e1 = (mv.y > 0.5f) ? bf16_of(dv.y * mv.y) : INVB;
            uint e2 = (mv.z > 0.5f) ? bf16_of(dv.z * mv.z) : INVB;
            uint e3 = (mv.w > 0.5f) ? bf16_of(dv.w * mv.w) : INVB;
            int pos = bs[l] + atomicAdd(&h2[l], 1);
            uint4 r;
            r.x = (uint)srcA[i];
            r.y = (uint)(ds[k] - l * per);
            r.z = e0 | (e1 << 16);
            r.w = e2 | (e3 << 16);
            recs[pos] = r;
        }
        __syncthreads();
    }
}

// -------------------------------------------------------------------- chain
// Merge a pre-merged candidate pair (vm, vs) into the packed (m, s) at p.
__device__ __forceinline__ void merge2(u64* p, float a, float b) {
    float vm = fmaxf(a, b);
    if (vm < -2e30f) return;                       // both invalid-sentinel
    float vs = __expf((a - vm) * INV_TAU) + __expf((b - vm) * INV_TAU);
    union U { u64 u; float2 f; };
    U o; o.u = *(volatile u64*)p;                  // CAS self-validates
    for (;;) {
        float m = o.f.x, s = o.f.y, nm, ns;
        float dlt = (vm - m) * INV_TAU;
        if (dlt > 0.f) { nm = vm; ns = s * __expf(-dlt) + vs; }
        else {
            if (dlt < -87.f) return;               // exp underflow: no-op (m only grows)
            nm = m; ns = s + vs * __expf(dlt);
        }
        U n; n.f.x = nm; n.f.y = ns;
        u64 got = atomicCAS(p, o.u, n.u);
        if (got == o.u) return;
        o.u = got;
    }
}

__global__ __launch_bounds__(256) void k_prop(
        const uint4* __restrict__ recs, const int* __restrict__ lvlBase,
        uint4* __restrict__ state, int lvl, int per) {
    int i0 = lvlBase[lvl], i1 = lvlBase[lvl + 1];
    int dbase = lvl * per;
    for (int i = i0 + blockIdx.x * blockDim.x + threadIdx.x; i < i1;
         i += gridDim.x * blockDim.x) {
        uint4 r = recs[i];
        uint4 st = state[r.x];
        float mr = __uint_as_float(st.x), sr = __uint_as_float(st.y);
        float mf = __uint_as_float(st.z), sf = __uint_as_float(st.w);
        float ar = (mr > -1e29f) ? mr + TAU_F * __logf(sr) : NEG_INF;
        float af = (mf > -1e29f) ? mf + TAU_F * __logf(sf) : NEG_INF;
        float d0 = f_of_bf16(r.z), d1 = f_of_bf16(r.z >> 16);
        float d2 = f_of_bf16(r.w), d3 = f_of_bf16(r.w >> 16);
        u64* pr = (u64*)&state[dbase + (int)r.y];
        merge2(pr,     ar + d0, af + d2);          // rise channel
        merge2(pr + 1, ar + d1, af + d3);          // fall channel
    }
}

// ----------------------------------------------------------------- epilogue
__device__ __forceinline__ float2 at_of(uint4 st) {
    float mr = __uint_as_float(st.x), sr = __uint_as_float(st.y);
    float mf = __uint_as_float(st.z), sf = __uint_as_float(st.w);
    float ar = (mr > -1e29f) ? mr + TAU_F * __logf(sr) : NEG_INF;
    float af = (mf > -1e29f) ? mf + TAU_F * __logf(sf) : NEG_INF;
    return make_float2(ar, af);
}

__global__ void k_fin(const uint4* __restrict__ state, int N,
                      float* __restrict__ at_all) {
    int i = blockIdx.x * blockDim.x + threadIdx.x;
    int st = gridDim.x * blockDim.x;
    for (; i < N; i += st) {
        float2 a = at_of(state[i]);
        at_all[2 * i]     = a.x;
        at_all[2 * i + 1] = a.y;
    }
}

__global__ void k_ep(const uint4* __restrict__ state, const int* __restrict__ ep,
                     const float* __restrict__ rat, int M,
                     float* __restrict__ out_ep, float* __restrict__ out_slack) {
    int i = blockIdx.x * blockDim.x + threadIdx.x;
    int st = gridDim.x * blockDim.x;
    const float thr = NEG_INF + 1.0f;   // == -1e30f in fp32
    for (; i < M; i += st) {
        float2 a = at_of(state[ep[i]]);
        float sx = (a.x > thr) ? a.x : 0.f;
        float sy = (a.y > thr) ? a.y : 0.f;
        out_ep[2 * i]        = sx;
        out_ep[2 * i + 1]    = sy;
        out_slack[2 * i]     = rat[2 * i]     - sx;
        out_slack[2 * i + 1] = rat[2 * i + 1] - sy;
    }
}

extern "C" void kernel_launch(void* const* d_in, const int* in_sizes, int n_in,
                              void* d_out, int out_size, void* d_ws, size_t ws_size,
                              hipStream_t stream) {
    const float* d_hat         = (const float*)d_in[0];
    const float* sta_mask      = (const float*)d_in[1];
    const float* input_arrival = (const float*)d_in[2];
    const float* rat_true      = (const float*)d_in[3];
    const int*   edge_src      = (const int*)d_in[4];
    const int*   edge_dst      = (const int*)d_in[5];
    const int*   endpoint_ids  = (const int*)d_in[6];

    const int E = in_sizes[4];
    const int N = in_sizes[2] / 2;
    const int M = in_sizes[3] / 2;
    const int L = 32;                 // max_level = 31; N % L == 0
    const int per = N / L;
    (void)n_in; (void)out_size; (void)ws_size;

    char* ws = (char*)d_ws;
    size_t off = 0;
    auto alloc = [&](size_t bytes) {
        void* p = ws + off;
        off = (off + bytes + 255) & ~((size_t)255);
        return p;
    };
    uint4* state   = (uint4*)alloc((size_t)N * 16);   // 16 MB
    uint4* recs    = (uint4*)alloc((size_t)E * 16);   // 128 MB
    int*   lvlCnt  = (int*)alloc(32 * 4);
    int*   lvlBase = (int*)alloc(33 * 4);
    int*   lvlCur  = (int*)alloc(32 * 4);

    hipMemsetAsync(lvlCnt, 0, 32 * 4, stream);
    k_init<<<(N + 255) / 256, 256, 0, stream>>>((const float2*)input_arrival, N, per, state);
    k_hist32<<<1024, 256, 0, stream>>>(edge_dst, E, per, lvlCnt);
    k_scan32<<<1, 64, 0, stream>>>(lvlCnt, lvlBase, lvlCur);

    int nChunk = (E + CHUNK - 1) / CHUNK;
    k_stage1<<<nChunk, 256, 0, stream>>>(edge_src, edge_dst,
                                         (const float4*)d_hat, (const float4*)sta_mask,
                                         E, per, lvlCur, recs);

    for (int lvl = 1; lvl < L; ++lvl)
        k_prop<<<1024, 256, 0, stream>>>(recs, lvlBase, state, lvl, per);

    float* at_all    = (float*)d_out;
    float* out_ep    = at_all + 2 * (size_t)N;
    float* out_slack = out_ep + 2 * (size_t)M;
    k_fin<<<(N + 255) / 256, 256, 0, stream>>>(state, N, at_all);
    k_ep<<<(M + 255) / 256, 256, 0, stream>>>(state, endpoint_ids, rat_true, M,
                                              out_ep, out_slack);
}

// Round 3
// 2087.989 us; speedup vs baseline: 1.1607x; 1.1607x over previous
//
#include <hip/hip_runtime.h>

// LevelwiseSTA v3: level-grouped compact records + two-phase (max, sum)
// fire-and-forget atomic chain. No CAS loops (round-2 lesson: CAS retry
// round-trips across XCDs serialized ~70us/level).
//
// state[node] = uint4 { encMax_r, encMax_f, bits(sum_r), bits(sum_f) }.
// encMax is a monotone uint encoding of float so atomicMax(uint) implements
// float max; 0 means "empty". at(node) is finalized on the fly as
// m + tau*log(sum) by any consumer. Sentinels: invalid d = -3e30 needs no
// special-casing (loses max to any valid candidate; underflows exp in sum;
// max <= -1e29 decodes to NEG_INF -> exact reachability classification).

#define NEG_INF  (-1e30f)
#define TAU_F    (0.07f)
#define INV_TAU  (1.0f / 0.07f)

typedef unsigned int uint;

__device__ __forceinline__ uint bf16_of(float f) {
    uint u = __float_as_uint(f);
    u += 0x7FFFu + ((u >> 16) & 1u);    // round to nearest even
    return u >> 16;
}
__device__ __forceinline__ float f_of_bf16(uint h) {
    return __uint_as_float((h & 0xFFFFu) << 16);
}
// monotone float<->uint for atomicMax
__device__ __forceinline__ uint enc_f(float f) {
    uint u = __float_as_uint(f);
    return (u & 0x80000000u) ? ~u : (u | 0x80000000u);
}
__device__ __forceinline__ float dec_f(uint e) {
    uint u = (e & 0x80000000u) ? (e & 0x7FFFFFFFu) : ~e;
    return __uint_as_float(u);
}

// finalize at = m + tau*log(s) from packed state (on-the-fly)
__device__ __forceinline__ float2 at_of(uint4 st) {
    float ar = NEG_INF, af = NEG_INF;
    if (st.x != 0u) {
        float m = dec_f(st.x);
        if (m > -1e29f) ar = m + TAU_F * __logf(__uint_as_float(st.z));
    }
    if (st.y != 0u) {
        float m = dec_f(st.y);
        if (m > -1e29f) af = m + TAU_F * __logf(__uint_as_float(st.w));
    }
    return make_float2(ar, af);
}

// ----------------------------------------------------------------- hist / scan
__global__ void k_hist32(const int* __restrict__ dst, int E, int per,
                         int* __restrict__ lvlCnt) {
    __shared__ int h[32];
    int t = threadIdx.x;
    if (t < 32) h[t] = 0;
    __syncthreads();
    int i = blockIdx.x * blockDim.x + t;
    int st = gridDim.x * blockDim.x;
    for (; i < E; i += st) {
        int l = dst[i] / per; if (l > 31) l = 31;
        atomicAdd(&h[l], 1);
    }
    __syncthreads();
    if (t < 32) atomicAdd(&lvlCnt[t], h[t]);
}

__global__ void k_scan32(const int* __restrict__ lvlCnt,
                         int* __restrict__ lvlBase, int* __restrict__ lvlCur) {
    if (threadIdx.x == 0) {
        int acc = 0;
        for (int l = 0; l < 32; ++l) {
            lvlBase[l] = acc; lvlCur[l] = acc; acc += lvlCnt[l];
        }
        lvlBase[32] = acc;
    }
}

// -------------------------------------------------------------------- init
// Level-0 nodes: m = input_arrival, s = 1  (at = m + tau*log 1 = m).
// Others: empty (0,0,0,0) -> filled by the chain.
__global__ void k_init(const float2* __restrict__ ia, int N, int per,
                       uint4* __restrict__ state) {
    int i = blockIdx.x * blockDim.x + threadIdx.x;
    int st = gridDim.x * blockDim.x;
    for (; i < N; i += st) {
        uint4 v;
        if (i < per) {
            float2 a = ia[i];
            v.x = enc_f(a.x); v.y = enc_f(a.y);
            v.z = __float_as_uint(1.0f); v.w = __float_as_uint(1.0f);
        } else {
            v.x = 0u; v.y = 0u; v.z = 0u; v.w = 0u;
        }
        state[i] = v;
    }
}

// ------------------------------------------------------------------- stage1
// Multisplit into 32 level buckets with per-chunk reservation (unchanged).
#define CHUNK 4096
__global__ __launch_bounds__(256) void k_stage1(
        const int* __restrict__ srcA, const int* __restrict__ dstA,
        const float4* __restrict__ dh, const float4* __restrict__ mk,
        int E, int per, int* __restrict__ lvlCur, uint4* __restrict__ recs) {
    __shared__ int h[32], bs[32], h2[32];
    int nChunk = (E + CHUNK - 1) / CHUNK;
    for (int c = blockIdx.x; c < nChunk; c += gridDim.x) {
        int t = threadIdx.x;
        if (t < 32) { h[t] = 0; h2[t] = 0; }
        __syncthreads();
        int base = c * CHUNK;
        unsigned char lv[16];
        int ds[16];
#pragma unroll
        for (int k = 0; k < 16; ++k) {
            int i = base + k * 256 + t;
            int l = 255, d = 0;
            if (i < E) {
                d = dstA[i];
                l = d / per; if (l > 31) l = 31;
                atomicAdd(&h[l], 1);
            }
            lv[k] = (unsigned char)l; ds[k] = d;
        }
        __syncthreads();
        if (t < 32 && h[t] > 0) bs[t] = atomicAdd(&lvlCur[t], h[t]);
        __syncthreads();
        const uint INVB = bf16_of(-3e30f);
#pragma unroll
        for (int k = 0; k < 16; ++k) {
            int i = base + k * 256 + t;
            if (i >= E) continue;
            int l = lv[k];
            float4 dv = dh[i];
            float4 mv = mk[i];
            uint e0 = (mv.x > 0.5f) ? bf16_of(dv.x * mv.x) : INVB;
            uint e1 = (mv.y > 0.5f) ? bf16_of(dv.y * mv.y) : INVB;
            uint e2 = (mv.z > 0.5f) ? bf16_of(dv.z * mv.z) : INVB;
            uint e3 = (mv.w > 0.5f) ? bf16_of(dv.w * mv.w) : INVB;
            int pos = bs[l] + atomicAdd(&h2[l], 1);
            uint4 r;
            r.x = (uint)srcA[i];
            r.y = (uint)(ds[k] - l * per);
            r.z = e0 | (e1 << 16);
            r.w = e2 | (e3 << 16);
            recs[pos] = r;
        }
        __syncthreads();
    }
}

// -------------------------------------------------------------- chain phase A
__global__ __launch_bounds__(256) void k_max(
        const uint4* __restrict__ recs, const int* __restrict__ lvlBase,
        uint* __restrict__ stw, int lvl, int per) {
    int i0 = lvlBase[lvl], i1 = lvlBase[lvl + 1];
    int dbase = lvl * per;
    for (int i = i0 + blockIdx.x * blockDim.x + threadIdx.x; i < i1;
         i += gridDim.x * blockDim.x) {
        uint4 r = recs[i];
        uint4 st = ((const uint4*)stw)[r.x];
        float2 a = at_of(st);
        float d0 = f_of_bf16(r.z), d1 = f_of_bf16(r.z >> 16);
        float d2 = f_of_bf16(r.w), d3 = f_of_bf16(r.w >> 16);
        uint er = max(enc_f(a.x + d0), enc_f(a.y + d2));
        uint ef = max(enc_f(a.x + d1), enc_f(a.y + d3));
        uint* dp = stw + 4u * (uint)(dbase + (int)r.y);
        atomicMax(dp + 0, er);
        atomicMax(dp + 1, ef);
    }
}

// -------------------------------------------------------------- chain phase B
__global__ __launch_bounds__(256) void k_sum(
        const uint4* __restrict__ recs, const int* __restrict__ lvlBase,
        uint* __restrict__ stw, int lvl, int per) {
    int i0 = lvlBase[lvl], i1 = lvlBase[lvl + 1];
    int dbase = lvl * per;
    for (int i = i0 + blockIdx.x * blockDim.x + threadIdx.x; i < i1;
         i += gridDim.x * blockDim.x) {
        uint4 r = recs[i];
        uint4 st = ((const uint4*)stw)[r.x];
        float2 a = at_of(st);
        float d0 = f_of_bf16(r.z), d1 = f_of_bf16(r.z >> 16);
        float d2 = f_of_bf16(r.w), d3 = f_of_bf16(r.w >> 16);
        int dn = dbase + (int)r.y;
        uint4 dst = ((const uint4*)stw)[dn];
        float mr = dec_f(dst.x), mf = dec_f(dst.y);
        float sr = __expf((a.x + d0 - mr) * INV_TAU) + __expf((a.y + d2 - mr) * INV_TAU);
        float sf = __expf((a.x + d1 - mf) * INV_TAU) + __expf((a.y + d3 - mf) * INV_TAU);
        float* fp = (float*)(stw + 4u * (uint)dn);
        atomicAdd(fp + 2, sr);
        atomicAdd(fp + 3, sf);
    }
}

// ----------------------------------------------------------------- epilogue
__global__ void k_fin(const uint4* __restrict__ state, int N,
                      float2* __restrict__ at_all) {
    int i = blockIdx.x * blockDim.x + threadIdx.x;
    int st = gridDim.x * blockDim.x;
    for (; i < N; i += st) at_all[i] = at_of(state[i]);
}

__global__ void k_ep(const uint4* __restrict__ state, const int* __restrict__ ep,
                     const float* __restrict__ rat, int M,
                     float* __restrict__ out_ep, float* __restrict__ out_slack) {
    int i = blockIdx.x * blockDim.x + threadIdx.x;
    int st = gridDim.x * blockDim.x;
    const float thr = NEG_INF + 1.0f;   // == -1e30f in fp32
    for (; i < M; i += st) {
        float2 a = at_of(state[ep[i]]);
        float sx = (a.x > thr) ? a.x : 0.f;
        float sy = (a.y > thr) ? a.y : 0.f;
        out_ep[2 * i]        = sx;
        out_ep[2 * i + 1]    = sy;
        out_slack[2 * i]     = rat[2 * i]     - sx;
        out_slack[2 * i + 1] = rat[2 * i + 1] - sy;
    }
}

extern "C" void kernel_launch(void* const* d_in, const int* in_sizes, int n_in,
                              void* d_out, int out_size, void* d_ws, size_t ws_size,
                              hipStream_t stream) {
    const float* d_hat         = (const float*)d_in[0];
    const float* sta_mask      = (const float*)d_in[1];
    const float* input_arrival = (const float*)d_in[2];
    const float* rat_true      = (const float*)d_in[3];
    const int*   edge_src      = (const int*)d_in[4];
    const int*   edge_dst      = (const int*)d_in[5];
    const int*   endpoint_ids  = (const int*)d_in[6];

    const int E = in_sizes[4];
    const int N = in_sizes[2] / 2;
    const int M = in_sizes[3] / 2;
    const int L = 32;                 // max_level = 31; N % L == 0
    const int per = N / L;
    (void)n_in; (void)out_size; (void)ws_size;

    char* ws = (char*)d_ws;
    size_t off = 0;
    auto alloc = [&](size_t bytes) {
        void* p = ws + off;
        off = (off + bytes + 255) & ~((size_t)255);
        return p;
    };
    uint4* state   = (uint4*)alloc((size_t)N * 16);   // 16 MB
    uint4* recs    = (uint4*)alloc((size_t)E * 16);   // 128 MB
    int*   lvlCnt  = (int*)alloc(32 * 4);
    int*   lvlBase = (int*)alloc(33 * 4);
    int*   lvlCur  = (int*)alloc(32 * 4);

    hipMemsetAsync(lvlCnt, 0, 32 * 4, stream);
    k_init<<<(N + 255) / 256, 256, 0, stream>>>((const float2*)input_arrival, N, per, state);
    k_hist32<<<1024, 256, 0, stream>>>(edge_dst, E, per, lvlCnt);
    k_scan32<<<1, 64, 0, stream>>>(lvlCnt, lvlBase, lvlCur);

    int nChunk = (E + CHUNK - 1) / CHUNK;
    k_stage1<<<nChunk, 256, 0, stream>>>(edge_src, edge_dst,
                                         (const float4*)d_hat, (const float4*)sta_mask,
                                         E, per, lvlCur, recs);

    for (int lvl = 1; lvl < L; ++lvl) {
        k_max<<<512, 256, 0, stream>>>(recs, lvlBase, (uint*)state, lvl, per);
        k_sum<<<512, 256, 0, stream>>>(recs, lvlBase, (uint*)state, lvl, per);
    }

    float* at_all    = (float*)d_out;
    float* out_ep    = at_all + 2 * (size_t)N;
    float* out_slack = out_ep + 2 * (size_t)M;
    k_fin<<<(N + 255) / 256, 256, 0, stream>>>(state, N, (float2*)at_all);
    k_ep<<<(M + 255) / 256, 256, 0, stream>>>(state, endpoint_ids, rat_true, M,
                                              out_ep, out_slack);
}